// Round 11
// baseline (113.491 us; speedup 1.0000x reference)
//
#include <hip/hip_runtime.h>
#include <math.h>

// CepstrumToImpulseResponse: h[0]=exp(c[0]); h[n] = (1/n) sum_{m=1..99} m*c[m]*h[n-m]
// B=65536, M=99, N=512. Output float32 [B, 512].
//
// Round-11: 4 lanes per batch row (lane l: taps m=25l+1..25l+25; lane3 m=100 pad)
// -> 4096 waves = 4 waves/SIMD (2-lane split capped at 2/SIMD; its 22% idle-issue
// was the residual). U=32 unroll, reversed tap loop, rn-table quad-prefetch into
// rotating registers, paired ds_write_b64 stores, flush overlapped with compute.
//
// Frames (all-static idx): lane l: hh[i] = h(n0+31-25l-i), i in [0,56].
//   step j, tap k: read i = k+32-j in [1,56]; reduce xor1+xor2 (quad sum).
//   fresh h(n0+j): lane0 -> slot 31-j; lane1 also -> slot 6-j for j<6 (its taps
//   m=26..31 reach intra-group values since U=32 > 25).
//   group end: bv1[d]=shr1(hh[d]) d=0..24 -> slots 7..31 (from lane l-1);
//   bv2[d]=shr2(hh[19+d]) d=0..5 -> slots 1..6 (from lane l-2; lanes 0/1 get
//   garbage into dead/self-overwritten slots); shift hh[56..32] <- hh[24..0].
//   Seeds: lane0 hh[32]=h0, lane1 hh[7]=h0 (h0 broadcast from quad lane 0).
// Output: per group lane0 stores 16 x float2 {pairs of consecutive samples} with
// 'prev' carrying the previous group's last sample -> cols 32g..32g+31; phases
// of 64 cols, double-buffered, flushed during the next phase's compute.

#define NROWS   64    // rows per 256-thread block (4 lanes per row)
#define STRIDE  66    // floats per stage row (264B: float2-aligned, bank stride 2)

__device__ __forceinline__ float dpp_xor1(float x) {   // quad_perm [1,0,3,2]
    return __int_as_float(__builtin_amdgcn_mov_dpp(__float_as_int(x), 0xB1, 0xF, 0xF, false));
}
__device__ __forceinline__ float dpp_xor2(float x) {   // quad_perm [2,3,0,1]
    return __int_as_float(__builtin_amdgcn_mov_dpp(__float_as_int(x), 0x4E, 0xF, 0xF, false));
}
__device__ __forceinline__ float dpp_shr1(float x) {   // row_shr:1 (lane l <- l-1)
    return __int_as_float(__builtin_amdgcn_mov_dpp(__float_as_int(x), 0x111, 0xF, 0xF, false));
}
__device__ __forceinline__ float dpp_shr2(float x) {   // row_shr:2 (lane l <- l-2)
    return __int_as_float(__builtin_amdgcn_mov_dpp(__float_as_int(x), 0x112, 0xF, 0xF, false));
}
__device__ __forceinline__ float dpp_bcast0(float x) { // quad_perm [0,0,0,0]
    return __int_as_float(__builtin_amdgcn_mov_dpp(__float_as_int(x), 0x00, 0xF, 0xF, false));
}

__global__ __launch_bounds__(256, 4)
void cep2ir_kernel(const float* __restrict__ c, float* __restrict__ out) {
    __shared__ float buf[2][NROWS * STRIDE];
    __shared__ float4 rn4[136];              // ((float*)rn4)[i] = 1/(i+1); 512..543 pad
    const int t = threadIdx.x;
    const int l = t & 3;                     // tap-block owner within quad
    const int lrow = t >> 2;                 // local row 0..63
    const int rowbase = blockIdx.x * NROWS;
    const float* cb = c + (size_t)(rowbase + lrow) * 100;
    float* outb = out + (size_t)rowbase * 512;

    // 1/n table (544 entries; >=511 are unused pad for OOB-safe prefetch).
    {
        float* rt = reinterpret_cast<float*>(rn4);
        rt[t]       = __builtin_amdgcn_rcpf((float)(t + 1));
        rt[t + 256] = __builtin_amdgcn_rcpf((float)(t + 257));
        if (t < 32) rt[t + 512] = 1.0f;
    }

    // Load 7 float4: lane l covers c[~25l .. 25l+27] (R6's verified loader).
    float e[28];
    {
        const float4* c4 = reinterpret_cast<const float4*>(cb);
        const int b0 = 6 * l + (l == 3 ? 1 : 0);
#pragma unroll
        for (int i = 0; i < 7; ++i) {
            int blk = b0 + i;
            if (l == 3 && i == 6) blk = 24;
            const float4 v = c4[blk];
            e[4 * i + 0] = v.x; e[4 * i + 1] = v.y;
            e[4 * i + 2] = v.z; e[4 * i + 3] = v.w;
        }
    }
    // w[k] = c[25l+k+1] * (25l+k+1); offset of c[25l+1] in e[]: {1,2,3,0}[l].
    float w[25];
    {
        const float lf = (float)l;
#pragma unroll
        for (int k = 0; k < 25; ++k) {
            const float ce = (l == 0) ? e[k + 1] : (l == 1) ? e[k + 2]
                           : (l == 2) ? e[k + 3] : e[k];
            w[k] = ce * (25.0f * lf + (float)(k + 1));
        }
        if (l == 3) w[24] = 0.0f;   // m=100 doesn't exist
    }

    // h0 = exp(c[0]) lives on quad lane 0; broadcast to the quad.
    const float h0 = dpp_bcast0(expf(e[0]));

    float hh[57];
#pragma unroll
    for (int k = 0; k < 57; ++k) hh[k] = 0.0f;
    hh[32] = (l == 0) ? h0 : 0.0f;   // lane0 frame: h(0) (n0=1)
    hh[7]  = (l == 1) ? h0 : 0.0f;   // lane1 frame: h(0)

    float prev = h0;                 // sample n0-1 for the pair-store (lane 0)
    __syncthreads();                 // rn table visible

    float4 r4a = rn4[0];             // rn for quad q=0 of group 0
    float4 r4b;

#pragma unroll 1
    for (int p = 0; p < 8; ++p) {
#pragma unroll 1
        for (int g = 0; g < 2; ++g) {
            const int gidx = 2 * p + g;
            const float4* rnp = &rn4[8 * gidx];
            // Overlapped flush of phase p-1: 4 chunks of 256 float2.
            if (p > 0) {
                const float* fb = buf[(p & 1) ^ 1];
                const int colbase = 64 * (p - 1);
                const int fr = t >> 5;            // 0..7
                const int fc = (t & 31) << 1;     // float2 col
#pragma unroll
                for (int i = 0; i < 4; ++i) {
                    const int r = 32 * g + 8 * i + fr;
                    const float2 v = *reinterpret_cast<const float2*>(&fb[r * STRIDE + fc]);
                    *reinterpret_cast<float2*>(&outb[(size_t)r * 512 + colbase + fc]) = v;
                }
            }
#pragma unroll
            for (int j = 0; j < 32; ++j) {
                // rn prefetch: one float4 (4 steps) ahead, rotating r4a/r4b.
                if ((j & 3) == 0) {
                    const int q = j >> 2;
                    if (q & 1) r4a = rnp[q + 1]; else r4b = rnp[q + 1];
                }
                float a0 = 0.f, a1 = 0.f;
                // Descending k: the freshest-dependent tap (k=0) issues LAST.
#pragma unroll
                for (int k = 24; k >= 0; --k) {
                    if ((k & 1) == 0) a0 = __builtin_fmaf(w[k], hh[k + 32 - j], a0);
                    else              a1 = __builtin_fmaf(w[k], hh[k + 32 - j], a1);
                }
                float s = a0 + a1;
                s += dpp_xor1(s);
                s += dpp_xor2(s);                   // full quad sum on all 4 lanes
                const float4& rq = (j & 4) ? r4b : r4a;
                const float rn = (j & 2) ? ((j & 1) ? rq.w : rq.z)
                                         : ((j & 1) ? rq.y : rq.x);
                const float hn = s * rn;
                hh[31 - j] = (l == 0) ? hn : hh[31 - j];
                if (j < 6) hh[6 - j] = (l == 1) ? hn : hh[6 - j];  // lane1 self-feed
            }
            // Pair-stores (lane 0): cols 32g..32g+31 = samples n0-1 .. n0+30.
            if (l == 0) {
                float* sc = &buf[p & 1][lrow * STRIDE + 32 * g];
                float2 v0; v0.x = prev; v0.y = hh[31];
                *reinterpret_cast<float2*>(&sc[0]) = v0;
#pragma unroll
                for (int i = 1; i < 16; ++i) {
                    float2 v; v.x = hh[32 - 2 * i]; v.y = hh[31 - 2 * i];
                    *reinterpret_cast<float2*>(&sc[2 * i]) = v;
                }
            }
            prev = hh[0];   // h(n0+31): first sample of next group's pair block
            // Boundary (pre-shift reads): shr1 fills slots 7..31, shr2 slots 1..6.
            float bv1[25], bv2[6];
#pragma unroll
            for (int d = 0; d < 25; ++d) bv1[d] = dpp_shr1(hh[d]);
#pragma unroll
            for (int d = 0; d < 6; ++d)  bv2[d] = dpp_shr2(hh[19 + d]);
            // Shift by 32.
#pragma unroll
            for (int k = 56; k >= 32; --k) hh[k] = hh[k - 32];
#pragma unroll
            for (int d = 0; d < 25; ++d) hh[7 + d] = bv1[d];
#pragma unroll
            for (int d = 0; d < 6; ++d)  hh[1 + d] = bv2[d];
        }
        __syncthreads();   // stage writes visible to next phase's flush
    }
    // Tail flush: phase 7's buffer (buf[1]) -> out cols 448..511.
    {
        const int fr = t >> 5;
        const int fc = (t & 31) << 1;
#pragma unroll 1
        for (int i = 0; i < 8; ++i) {
            const int r = 8 * i + fr;
            const float2 v = *reinterpret_cast<const float2*>(&buf[1][r * STRIDE + fc]);
            *reinterpret_cast<float2*>(&outb[(size_t)r * 512 + 448 + fc]) = v;
        }
    }
}

extern "C" void kernel_launch(void* const* d_in, const int* in_sizes, int n_in,
                              void* d_out, int out_size, void* d_ws, size_t ws_size,
                              hipStream_t stream) {
    const float* c = (const float*)d_in[0];
    float* out = (float*)d_out;
    // 4 lanes per row: 65536 rows * 4 / 256 = 1024 blocks (4 per CU).
    cep2ir_kernel<<<1024, 256, 0, stream>>>(c, out);
}

// Round 12
// 101.287 us; speedup vs baseline: 1.1205x; 1.1205x over previous
//
#include <hip/hip_runtime.h>
#include <math.h>

// CepstrumToImpulseResponse: h[0]=exp(c[0]); h[n] = (1/n) sum_{m=1..99} m*c[m]*h[n-m]
// B=65536, M=99, N=512. Output float32 [B, 512].
//
// FINAL (round-10 structure, reverted after round-11's 4-lane experiment
// regressed 101 -> 113.5 us): 2 lanes per batch row (A: taps m=1..50,
// B: m=51..99), uniform 82-slot register window, all-static indexing, U=32
// time unroll, DPP xor-1 pair reduce, 1/n LDS table, reversed tap loop
// (hn-dependent FMA issues last), 8 phases x 64 cols with double-buffered
// LDS stage and flush overlapped into the next phase's compute.
//
// Ceiling accounting (measured): 6.67 GFLOP / (103 TF sustained fp32 FMA
// x 87% static FMA density x ~79% VALU busy at 2 waves/SIMD) ~ 101 us.
// 4-lane split (R11): occupancy 2x but issue +13% -> net loss. cndmask,
// DPP-reduce, shift, rn-read each minimized or proven load-bearing.
//
// Index map (U=32): frame A: hh[i]=h(n0+31-i); B: hh[i]=h(n0-19-i).
//   step j, tap k: read s = k+32-j in [1,81]; fresh h(n0+j) -> slot 31-j (A).
//   group end: bv[i]=xor1(hh[18+i]) pre-shift; shift hh[81..32]<-hh[49..0];
//   hh[0..31]<-bv. Seed h(0) at slot 32. Post-shift hh[32] = h(32*(gidx+1)).
// Stage stride 66: 264B rows (8B-aligned float2) and bank stride 2 -> worst
// 2-way LDS conflicts (free). Col 64 = dump slot for the carry store.

#define NROWS   128
#define STRIDE  66    // 64 data cols + dump col 64 + pad

__device__ __forceinline__ float dpp_xor1(float x) {   // quad_perm [1,0,3,2]
    return __int_as_float(__builtin_amdgcn_mov_dpp(__float_as_int(x), 0xB1, 0xF, 0xF, false));
}

__global__ __launch_bounds__(256, 2)
void cep2ir_kernel(const float* __restrict__ c, float* __restrict__ out) {
    __shared__ float buf[2][NROWS * STRIDE];
    __shared__ float4 rn4[128];              // ((float*)rn4)[i] = 1/(i+1), i=0..510
    const int t = threadIdx.x;
    const int lrow = t >> 1;                 // local row 0..127
    const bool isA = (t & 1) == 0;
    const int rowbase = blockIdx.x * NROWS;
    const float* cb = c + (size_t)(rowbase + lrow) * 100;
    float* outb = out + (size_t)rowbase * 512;

    // 1/n table: each thread fills entries t and t+256.
    {
        float* rt = reinterpret_cast<float*>(rn4);
        rt[t]       = __builtin_amdgcn_rcpf((float)(t + 1));
        rt[t + 256] = __builtin_amdgcn_rcpf((float)(t + 257));
    }

    // Load 13 float4 = 52 floats: A covers c[0..51], B covers c[48..99].
    float e[52];
    {
        const float4* c4 = reinterpret_cast<const float4*>(cb);
        const int f4b = isA ? 0 : 12;
#pragma unroll
        for (int i = 0; i < 13; ++i) {
            const float4 v = c4[f4b + i];
            e[4 * i + 0] = v.x; e[4 * i + 1] = v.y;
            e[4 * i + 2] = v.z; e[4 * i + 3] = v.w;
        }
    }
    // Weights: A: w[k]=c[k+1]*(k+1); B: w[k]=c[51+k]*(51+k), k=0..48; w[49]=0 on B.
    float w[50];
#pragma unroll
    for (int k = 0; k < 49; ++k)
        w[k] = (isA ? e[k + 1] : e[k + 3]) * (isA ? (float)(k + 1) : (float)(k + 51));
    w[49] = isA ? e[50] * 50.0f : 0.0f;

    const float h0 = expf(e[0]);  // meaningful on lane A

    float hh[82];
#pragma unroll
    for (int k = 0; k < 82; ++k) hh[k] = 0.0f;
    hh[32] = isA ? h0 : 0.0f;     // h(0) in A frame (n0=1)

    if (isA) buf[0][lrow * STRIDE] = h0;   // col 0 of phase 0
    __syncthreads();                       // rn table + h0 staged

#pragma unroll 1
    for (int p = 0; p < 8; ++p) {
        // Carry h(64p) (post-shift hh[32] from phase p-1) -> col 0 of this buffer.
        if (p > 0 && isA) buf[p & 1][lrow * STRIDE] = hh[32];
#pragma unroll 1
        for (int g = 0; g < 2; ++g) {
            const int gidx = 2 * p + g;
            // 1/n for the 32 steps: broadcast ds_read_b128 x8, off the chain.
            float4 r4[8];
            {
                const float4* rp = &rn4[8 * gidx];
#pragma unroll
                for (int i = 0; i < 8; ++i) r4[i] = rp[i];
            }
            // Interleaved flush chunk: 8 float2 row-segments of phase p-1's buffer.
            if (p > 0) {
                const float* fb = buf[(p & 1) ^ 1];
                const int colbase = 64 * (p - 1);
#pragma unroll
                for (int i = 0; i < 8; ++i) {
                    const int idx = (8 * g + i) * 256 + t;
                    const int r = idx >> 5;          // 0..127
                    const int c2 = idx & 31;         // float2 index within 64 cols
                    const float2 v = *reinterpret_cast<const float2*>(&fb[r * STRIDE + 2 * c2]);
                    *reinterpret_cast<float2*>(&outb[(size_t)r * 512 + colbase + 2 * c2]) = v;
                }
            }
#pragma unroll
            for (int j = 0; j < 32; ++j) {
                float a0 = 0.f, a1 = 0.f;
                // Descending k: the hn-dependent tap (k=0) issues LAST.
#pragma unroll
                for (int k = 49; k >= 0; --k) {
                    if ((k & 1) == 0) a0 = __builtin_fmaf(w[k], hh[k + 32 - j], a0);
                    else              a1 = __builtin_fmaf(w[k], hh[k + 32 - j], a1);
                }
                float s = a0 + a1;
                s += dpp_xor1(s);                       // pair reduce
                const float rn = (j & 2) ? ((j & 1) ? r4[j >> 2].w : r4[j >> 2].z)
                                         : ((j & 1) ? r4[j >> 2].y : r4[j >> 2].x);
                const float hn = s * rn;
                hh[31 - j] = isA ? hn : hh[31 - j];     // only A's frame takes fresh h
            }
            // Batched stores: A's hh[31..0] = h(n0..n0+31) -> cols 1+32g..32+32g.
            // (g==1, j==31 lands in dump col 64; that value re-emerges as carry.)
            if (isA) {
                float* sc = &buf[p & 1][lrow * STRIDE + 1 + 32 * g];
#pragma unroll
                for (int j = 0; j < 32; ++j) sc[j] = hh[31 - j];
            }
            // Boundary (pre-shift reads): B's next slots 0..31 = A's h(n0+13..n0-18).
            float bv[32];
#pragma unroll
            for (int i = 0; i < 32; ++i) bv[i] = dpp_xor1(hh[18 + i]);
            // Shift window by 32 (descending; read range 49..0 disjoint from writes).
#pragma unroll
            for (int k = 81; k >= 32; --k) hh[k] = hh[k - 32];
#pragma unroll
            for (int i = 0; i < 32; ++i) hh[i] = bv[i];  // A's copies are dead slots
        }
        __syncthreads();   // compute writes visible to next phase's flush readers
    }
    // Tail flush: phase 7's buffer (buf[1]) -> out cols 448..511.
#pragma unroll 1
    for (int i = 0; i < 16; ++i) {
        const int idx = i * 256 + t;
        const int r = idx >> 5;
        const int c2 = idx & 31;
        const float2 v = *reinterpret_cast<const float2*>(&buf[1][r * STRIDE + 2 * c2]);
        *reinterpret_cast<float2*>(&outb[(size_t)r * 512 + 448 + 2 * c2]) = v;
    }
}

extern "C" void kernel_launch(void* const* d_in, const int* in_sizes, int n_in,
                              void* d_out, int out_size, void* d_ws, size_t ws_size,
                              hipStream_t stream) {
    const float* c = (const float*)d_in[0];
    float* out = (float*)d_out;
    // 2 lanes per row: 65536 rows * 2 / 256 = 512 blocks (2 per CU).
    cep2ir_kernel<<<512, 256, 0, stream>>>(c, out);
}